// Round 2
// baseline (325.892 us; speedup 1.0000x reference)
//
#include <hip/hip_runtime.h>

typedef float f4_t __attribute__((ext_vector_type(4)));
typedef __bf16 bf8_t __attribute__((ext_vector_type(8)));
typedef __bf16 bf4_t __attribute__((ext_vector_type(4)));

#define MFMA16(a,b,c) __builtin_amdgcn_mfma_f32_16x16x32_bf16((a),(b),(c),0,0,0)

static constexpr float kScale = 0.17677669529663687f; // 1/sqrt(32)

// ---------------------------------------------------------------------------
// K0: fold router query through Wq1 and Wk1:
//   q1[r][d'] = router[r]@Wq1 + bq1
//   q1t[j=h*8+r][e] = kScale * sum_d q1[r][h*32+d] * Wk1[e][h*32+d]
//   c1[j]           = kScale * sum_d q1[r][h*32+d] * bk1[h*32+d]
// ---------------------------------------------------------------------------
__global__ __launch_bounds__(256) void k0_fold(
    const float* __restrict__ router, const float* __restrict__ Wq1,
    const float* __restrict__ bq1, const float* __restrict__ Wk1,
    const float* __restrict__ bk1, float* __restrict__ q1t,
    float* __restrict__ c1)
{
  __shared__ float q1[8][128];
  const int t = threadIdx.x;
  for (int idx = t; idx < 1024; idx += 256) {
    int r = idx >> 7, dp = idx & 127;
    float acc = bq1[dp];
    for (int e = 0; e < 128; ++e) acc += router[r*128 + e] * Wq1[e*128 + dp];
    q1[r][dp] = acc;
  }
  __syncthreads();
  for (int idx = t; idx < 4096; idx += 256) {
    int j = idx >> 7, e = idx & 127;
    int h = j >> 3, r = j & 7;
    float acc = 0.f;
    for (int d = 0; d < 32; ++d) acc += q1[r][h*32 + d] * Wk1[e*128 + h*32 + d];
    q1t[idx] = acc * kScale;
  }
  if (t < 32) {
    int h = t >> 3, r = t & 7;
    float acc = 0.f;
    for (int d = 0; d < 32; ++d) acc += q1[r][h*32 + d] * bk1[h*32 + d];
    c1[t] = acc * kScale;
  }
}

// ---------------------------------------------------------------------------
// K1: stage-1 attention reduction. One block = one half (1024 rows) of one
// batch. Computes (unnormalized) xa[j][dim] = sum_s exp(x_s.q1t[j]+c1[j])*x_s
// and l[j] = sum_s exp(...). MFMA 16x16x32 bf16 for both products.
// ---------------------------------------------------------------------------
__global__ __launch_bounds__(512) void k1_stage1(
    const float* __restrict__ Z, const float* __restrict__ q1t_g,
    const float* __restrict__ c1_g, float* __restrict__ xap,
    float* __restrict__ lp)
{
  __shared__ __bf16 xb[64][136];   // x tile, row-major [pos][dim]
  __shared__ __bf16 xT[128][72];   // transposed   [dim][pos]
  __shared__ __bf16 PT[32][72];    // P            [j][pos]
  __shared__ __bf16 q1t[32][136];  // folded query [j][e]
  __shared__ float lds_l[32];

  const int tid = threadIdx.x;
  const int bid = blockIdx.x;                 // = batch*2 + half
  const float* xbase = Z + (size_t)bid * (1024 * 128);

  for (int idx = tid; idx < 4096; idx += 512)
    q1t[idx >> 7][idx & 127] = (__bf16)q1t_g[idx];
  if (tid < 32) lds_l[tid] = 0.f;

  const int lane = tid & 63;
  const int w = tid >> 6;       // 8 waves
  const int lc = lane & 15;
  const int lg = lane >> 4;
  const int ms = w >> 2;        // j-tile (0..1) for scores & xa
  const int ns = w & 3;         // pos-tile (0..3) for scores
  float c1v[4];
#pragma unroll
  for (int r2 = 0; r2 < 4; ++r2) c1v[r2] = c1_g[ms*16 + lg*4 + r2];

  const f4_t fzero = {0.f, 0.f, 0.f, 0.f};
  f4_t accxa[2] = { fzero, fzero };
  float Lacc[4] = {0.f, 0.f, 0.f, 0.f};

  __syncthreads();

  for (int tile = 0; tile < 16; ++tile) {
    const float* xt = xbase + tile * (64 * 128);
    // stage 64x128 f32 -> bf16 LDS (coalesced float4 loads)
#pragma unroll
    for (int i = 0; i < 4; ++i) {
      int f = tid + i*512;
      int pos = f >> 5, d0 = (f & 31) << 2;
      float4 v = *(const float4*)(xt + pos*128 + d0);
      bf4_t b4 = { (__bf16)v.x, (__bf16)v.y, (__bf16)v.z, (__bf16)v.w };
      *(bf4_t*)&xb[pos][d0] = b4;
    }
    __syncthreads();
    // transpose xb -> xT (each thread: 8-pos strip of one dim)
#pragma unroll
    for (int s = 0; s < 2; ++s) {
      int u = tid + s*512;
      int dim = u & 127, pb = (u >> 7) << 3;
      bf8_t t8;
#pragma unroll
      for (int p = 0; p < 8; ++p) t8[p] = xb[pb + p][dim];
      *(bf8_t*)&xT[dim][pb] = t8;
    }
    // scores: ST[j=32][pos=64] = q1t(32x128) @ x^T    (A=q1t, B=xb rows)
    f4_t sacc = fzero;
#pragma unroll
    for (int ks = 0; ks < 4; ++ks) {
      bf8_t a = *(const bf8_t*)&q1t[ms*16 + lc][ks*32 + lg*8];
      bf8_t b = *(const bf8_t*)&xb[ns*16 + lc][ks*32 + lg*8];
      sacc = MFMA16(a, b, sacc);
    }
    // P = exp(s + c1)  (scores ~1e-3: no max subtraction needed)
    const int posn = ns*16 + lc;
#pragma unroll
    for (int r2 = 0; r2 < 4; ++r2) {
      float p = __expf(sacc[r2] + c1v[r2]);
      Lacc[r2] += p;
      PT[ms*16 + lg*4 + r2][posn] = (__bf16)p;
    }
    __syncthreads();
    // xa[j=32][dim=128] += P(32x64) @ x(64x128)   (A=PT rows, B=xT rows)
#pragma unroll
    for (int nt = 0; nt < 2; ++nt) {
      const int dimt = (ns << 1) + nt;
#pragma unroll
      for (int ks = 0; ks < 2; ++ks) {
        bf8_t a = *(const bf8_t*)&PT[ms*16 + lc][ks*32 + lg*8];
        bf8_t b = *(const bf8_t*)&xT[dimt*16 + lc][ks*32 + lg*8];
        accxa[nt] = MFMA16(a, b, accxa[nt]);
      }
    }
    __syncthreads();
  }

  // reduce l over pos (16 lanes) then across waves
#pragma unroll
  for (int r2 = 0; r2 < 4; ++r2) {
    float v = Lacc[r2];
    v += __shfl_xor(v, 1);
    v += __shfl_xor(v, 2);
    v += __shfl_xor(v, 4);
    v += __shfl_xor(v, 8);
    if (lc == 0) atomicAdd(&lds_l[ms*16 + lg*4 + r2], v);
  }
  __syncthreads();

  float* xo = xap + (size_t)bid * 4096;
#pragma unroll
  for (int nt = 0; nt < 2; ++nt) {
    const int dim = ((ns << 1) + nt)*16 + lc;
#pragma unroll
    for (int r2 = 0; r2 < 4; ++r2) {
      int j = ms*16 + lg*4 + r2;
      xo[j*128 + dim] = accxa[nt][r2];
    }
  }
  if (tid < 32) lp[bid*32 + tid] = lds_l[tid];
}

// ---------------------------------------------------------------------------
// K1b: per-batch epilogue + stage-2 folding. One block per batch.
//  xa -> out1 -> rb -> k2,v2 -> kt2 (folded keys), c2, vt2 (folded values^T)
// ---------------------------------------------------------------------------
__global__ __launch_bounds__(256) void k1b_mid(
    const float* __restrict__ xap, const float* __restrict__ lp,
    const float* __restrict__ Wv1, const float* __restrict__ bv1,
    const float* __restrict__ Wo1, const float* __restrict__ bo1,
    const float* __restrict__ Wk2, const float* __restrict__ bk2,
    const float* __restrict__ Wv2, const float* __restrict__ bv2,
    const float* __restrict__ Wq2, const float* __restrict__ bq2,
    const float* __restrict__ Wo2,
    float* __restrict__ kt2, float* __restrict__ c2, float* __restrict__ vt2)
{
  __shared__ float xa[32][129];
  __shared__ float invl[32];
  __shared__ float out1[8][128];
  __shared__ float rb[8][128];
  __shared__ float k2s[8][128];
  __shared__ float v2s[8][128];

  const int t = threadIdx.x, b = blockIdx.x;
  const float* p0 = xap + (size_t)(b*2) * 4096;
  const float* p1 = xap + (size_t)(b*2 + 1) * 4096;
  for (int idx = t; idx < 4096; idx += 256)
    xa[idx >> 7][idx & 127] = p0[idx] + p1[idx];
  if (t < 32) invl[t] = 1.f / (lp[b*64 + t] + lp[b*64 + 32 + t]);
  __syncthreads();

  for (int idx = t; idx < 1024; idx += 256) {
    int r = idx >> 7, hd = idx & 127, h = hd >> 5;
    int j = h*8 + r;
    float acc = 0.f;
    for (int e = 0; e < 128; ++e) acc += xa[j][e] * Wv1[e*128 + hd];
    out1[r][hd] = acc * invl[j] + bv1[hd];
  }
  __syncthreads();
  for (int idx = t; idx < 1024; idx += 256) {
    int r = idx >> 7, e2 = idx & 127;
    float acc = bo1[e2];
    for (int hd = 0; hd < 128; ++hd) acc += out1[r][hd] * Wo1[hd*128 + e2];
    rb[r][e2] = acc;
  }
  __syncthreads();
  for (int idx = t; idx < 2048; idx += 256) {
    int sel = idx >> 10;
    int r = (idx >> 7) & 7, hd = idx & 127;
    const float* W = sel ? Wv2 : Wk2;
    const float* bb = sel ? bv2 : bk2;
    float acc = bb[hd];
    for (int e = 0; e < 128; ++e) acc += rb[r][e] * W[e*128 + hd];
    float (*dst)[128] = sel ? v2s : k2s;
    dst[r][hd] = acc;
  }
  __syncthreads();
  for (int idx = t; idx < 4096; idx += 256) {
    int j = idx >> 7, e = idx & 127;
    int h = j >> 3, r = j & 7;
    float acck = 0.f, accv = 0.f;
    for (int d = 0; d < 32; ++d) {
      acck += Wq2[e*128 + h*32 + d] * k2s[r][h*32 + d];
      accv += v2s[r][h*32 + d] * Wo2[(h*32 + d)*128 + e];
    }
    kt2[(size_t)b*4096 + j*128 + e] = acck * kScale;  // [j][e]
    vt2[(size_t)b*4096 + e*32 + j] = accv;            // [e][j]  (transposed)
  }
  if (t < 32) {
    int h = t >> 3, r = t & 7;
    float acc = 0.f;
    for (int d = 0; d < 32; ++d) acc += bq2[h*32 + d] * k2s[r][h*32 + d];
    c2[b*32 + t] = acc * kScale;
  }
}

// ---------------------------------------------------------------------------
// K2: stage-2 attention + residual + LayerNorm. One block = 64 positions.
//  S2 = x @ kt2^T + c2 ; per-head softmax over 8 ; rr = A2 @ vt2^T + bo2
//  y = LN(x + rr) * gamma + beta
// ---------------------------------------------------------------------------
__global__ __launch_bounds__(256) void k2_stage2(
    const float* __restrict__ Z, const float* __restrict__ kt2,
    const float* __restrict__ c2g, const float* __restrict__ vt2,
    const float* __restrict__ bo2, const float* __restrict__ gamma,
    const float* __restrict__ beta, float* __restrict__ out)
{
  __shared__ __bf16 xb[64][136];
  __shared__ __bf16 kt[32][136];
  __shared__ __bf16 vT[128][56];
  __shared__ __bf16 P2[64][56];

  const int tid = threadIdx.x;
  const int bid = blockIdx.x;
  const int batch = bid >> 5;
  const size_t rowbase = (size_t)bid * (64 * 128);
  const float* x = Z + rowbase;
  float* y = out + rowbase;

  const float* ktg = kt2 + (size_t)batch * 4096;
  const float* vtg = vt2 + (size_t)batch * 4096;
  for (int idx = tid; idx < 4096; idx += 256) {
    kt[idx >> 7][idx & 127] = (__bf16)ktg[idx];
    vT[idx >> 5][idx & 31] = (__bf16)vtg[idx];
  }
#pragma unroll
  for (int i = 0; i < 8; ++i) {
    int f = tid + i*256;
    int pos = f >> 5, d0 = (f & 31) << 2;
    float4 v = *(const float4*)(x + pos*128 + d0);
    bf4_t b4 = { (__bf16)v.x, (__bf16)v.y, (__bf16)v.z, (__bf16)v.w };
    *(bf4_t*)&xb[pos][d0] = b4;
  }
  __syncthreads();

  const int lane = tid & 63;
  const int w = tid >> 6;    // 4 waves, pos-tile = w
  const int lc = lane & 15;
  const int lg = lane >> 4;

  const f4_t fzero = {0.f, 0.f, 0.f, 0.f};

  // scores: S2[pos=64][j=32] = x @ kt^T
  f4_t sacc[2] = { fzero, fzero };
#pragma unroll
  for (int ks = 0; ks < 4; ++ks) {
    bf8_t a = *(const bf8_t*)&xb[w*16 + lc][ks*32 + lg*8];
#pragma unroll
    for (int nt = 0; nt < 2; ++nt) {
      bf8_t b = *(const bf8_t*)&kt[nt*16 + lc][ks*32 + lg*8];
      sacc[nt] = MFMA16(a, b, sacc[nt]);
    }
  }
  float c2v[2] = { c2g[batch*32 + lc], c2g[batch*32 + 16 + lc] };
  // per-head softmax over 8 routers (lanes differing in bits 0..2)
#pragma unroll
  for (int nt = 0; nt < 2; ++nt) {
#pragma unroll
    for (int r2 = 0; r2 < 4; ++r2) {
      float s = sacc[nt][r2] + c2v[nt];
      float m = s;
      m = fmaxf(m, __shfl_xor(m, 1));
      m = fmaxf(m, __shfl_xor(m, 2));
      m = fmaxf(m, __shfl_xor(m, 4));
      float p = __expf(s - m);
      float sum = p;
      sum += __shfl_xor(sum, 1);
      sum += __shfl_xor(sum, 2);
      sum += __shfl_xor(sum, 4);
      P2[w*16 + lg*4 + r2][nt*16 + lc] = (__bf16)(p / sum);
    }
  }
  __syncthreads();

  // rr[pos=64][dim=128] = P2(64x32) @ vT^T   (K=32: single MFMA per tile)
  bf8_t pa = *(const bf8_t*)&P2[w*16 + lc][lg*8];
  f4_t racc[8];
#pragma unroll
  for (int nt = 0; nt < 8; ++nt) {
    bf8_t b = *(const bf8_t*)&vT[nt*16 + lc][lg*8];
    racc[nt] = MFMA16(pa, b, fzero);
  }

  float bo2v[8], gv[8], bv[8];
#pragma unroll
  for (int nt = 0; nt < 8; ++nt) {
    int dd = nt*16 + lc;
    bo2v[nt] = bo2[dd]; gv[nt] = gamma[dd]; bv[nt] = beta[dd];
  }
#pragma unroll
  for (int r2 = 0; r2 < 4; ++r2) {
    int pos = w*16 + lg*4 + r2;
    float vv[8];
    float s1 = 0.f, s2 = 0.f;
#pragma unroll
    for (int nt = 0; nt < 8; ++nt) {
      float xv = (float)xb[pos][nt*16 + lc];
      float tv = racc[nt][r2] + bo2v[nt] + xv;
      vv[nt] = tv; s1 += tv; s2 += tv*tv;
    }
    s1 += __shfl_xor(s1, 1); s1 += __shfl_xor(s1, 2);
    s1 += __shfl_xor(s1, 4); s1 += __shfl_xor(s1, 8);
    s2 += __shfl_xor(s2, 1); s2 += __shfl_xor(s2, 2);
    s2 += __shfl_xor(s2, 4); s2 += __shfl_xor(s2, 8);
    float mean = s1 * (1.f/128.f);
    float var = s2 * (1.f/128.f) - mean*mean;
    float rstd = rsqrtf(var + 1e-5f);
#pragma unroll
    for (int nt = 0; nt < 8; ++nt)
      y[pos*128 + nt*16 + lc] = (vv[nt] - mean) * rstd * gv[nt] + bv[nt];
  }
}

// ---------------------------------------------------------------------------
extern "C" void kernel_launch(void* const* d_in, const int* in_sizes, int n_in,
                              void* d_out, int out_size, void* d_ws, size_t ws_size,
                              hipStream_t stream)
{
  const float* Z     = (const float*)d_in[0];
  const float* router= (const float*)d_in[1];
  const float* Wq1   = (const float*)d_in[2];
  const float* bq1   = (const float*)d_in[3];
  const float* Wk1   = (const float*)d_in[4];
  const float* bk1   = (const float*)d_in[5];
  const float* Wv1   = (const float*)d_in[6];
  const float* bv1   = (const float*)d_in[7];
  const float* Wo1   = (const float*)d_in[8];
  const float* bo1   = (const float*)d_in[9];
  const float* Wq2   = (const float*)d_in[10];
  const float* bq2   = (const float*)d_in[11];
  const float* Wk2   = (const float*)d_in[12];
  const float* bk2   = (const float*)d_in[13];
  const float* Wv2   = (const float*)d_in[14];
  const float* bv2   = (const float*)d_in[15];
  const float* Wo2   = (const float*)d_in[16];
  const float* bo2   = (const float*)d_in[17];
  const float* gamma = (const float*)d_in[18];
  const float* beta  = (const float*)d_in[19];
  float* out = (float*)d_out;

  float* wsf = (float*)d_ws;
  float* q1t = wsf;                    // 4096
  float* c1  = wsf + 4096;             // 32 (+pad)
  float* xap = wsf + 4352;             // 512*4096
  float* lp  = xap + (size_t)512*4096; // 512*32
  float* kt2 = lp  + 512*32;           // 256*4096
  float* c2  = kt2 + (size_t)256*4096; // 256*32
  float* vt2 = c2  + 256*32;           // 256*4096
  (void)in_sizes; (void)n_in; (void)out_size; (void)ws_size;

  k0_fold<<<dim3(1), dim3(256), 0, stream>>>(router, Wq1, bq1, Wk1, bk1, q1t, c1);
  k1_stage1<<<dim3(512), dim3(512), 0, stream>>>(Z, q1t, c1, xap, lp);
  k1b_mid<<<dim3(256), dim3(256), 0, stream>>>(xap, lp, Wv1, bv1, Wo1, bo1,
                                               Wk2, bk2, Wv2, bv2, Wq2, bq2, Wo2,
                                               kt2, c2, vt2);
  k2_stage2<<<dim3(8192), dim3(256), 0, stream>>>(Z, kt2, c2, vt2, bo2, gamma, beta, out);
}

// Round 4
// 298.845 us; speedup vs baseline: 1.0905x; 1.0905x over previous
//
#include <hip/hip_runtime.h>

typedef float f4_t __attribute__((ext_vector_type(4)));
typedef __bf16 bf8_t __attribute__((ext_vector_type(8)));
typedef __bf16 bf4_t __attribute__((ext_vector_type(4)));

#define MFMA16(a,b,c) __builtin_amdgcn_mfma_f32_16x16x32_bf16((a),(b),(c),0,0,0)

static constexpr float kScale = 0.17677669529663687f; // 1/sqrt(32)

// ---------------------------------------------------------------------------
// K0: fold router query through Wq1 and Wk1 -> q1t (bf16), c1 (f32)
// ---------------------------------------------------------------------------
__global__ __launch_bounds__(256) void k0_fold(
    const float* __restrict__ router, const float* __restrict__ Wq1,
    const float* __restrict__ bq1, const float* __restrict__ Wk1,
    const float* __restrict__ bk1, __bf16* __restrict__ q1t,
    float* __restrict__ c1)
{
  __shared__ float q1[8][128];
  const int t = threadIdx.x;
  for (int idx = t; idx < 1024; idx += 256) {
    int r = idx >> 7, dp = idx & 127;
    float acc = bq1[dp];
    for (int e = 0; e < 128; ++e) acc += router[r*128 + e] * Wq1[e*128 + dp];
    q1[r][dp] = acc;
  }
  __syncthreads();
  for (int idx = t; idx < 4096; idx += 256) {
    int j = idx >> 7, e = idx & 127;
    int h = j >> 3, r = j & 7;
    float acc = 0.f;
    for (int d = 0; d < 32; ++d) acc += q1[r][h*32 + d] * Wk1[e*128 + h*32 + d];
    q1t[idx] = (__bf16)(acc * kScale);
  }
  if (t < 32) {
    int h = t >> 3, r = t & 7;
    float acc = 0.f;
    for (int d = 0; d < 32; ++d) acc += q1[r][h*32 + d] * bk1[h*32 + d];
    c1[t] = acc * kScale;
  }
}

// ---------------------------------------------------------------------------
// K1: stage-1 attention reduction. One block = 1024 rows (half batch).
// xa[j][dim] = sum_s exp(x_s.q1t[j]+c1[j])*x_s ; l[j] = sum_s exp(...)
// ---------------------------------------------------------------------------
__global__ __launch_bounds__(512) void k1_stage1(
    const float* __restrict__ Z, const __bf16* __restrict__ q1t_g,
    const float* __restrict__ c1_g, float* __restrict__ xap,
    float* __restrict__ lp)
{
  __shared__ __bf16 xb[64][136];   // x tile, row-major [pos][dim]
  __shared__ __bf16 xT[128][72];   // transposed   [dim][pos]
  __shared__ __bf16 PT[32][72];    // P            [j][pos]
  __shared__ __bf16 q1t[32][136];  // folded query [j][e]
  __shared__ float lds_l[32];

  const int tid = threadIdx.x;
  const int bid = blockIdx.x;                 // = batch*2 + half
  const float* xbase = Z + (size_t)bid * (1024 * 128);

  { // q1t: 4096 bf16 = 512 x 16B chunks, one per thread
    int j = tid >> 4, e0 = (tid & 15) << 3;
    *(uint4*)&q1t[j][e0] = *(const uint4*)(q1t_g + j*128 + e0);
  }
  if (tid < 32) lds_l[tid] = 0.f;

  const int lane = tid & 63;
  const int w = tid >> 6;       // 8 waves
  const int lc = lane & 15;
  const int lg = lane >> 4;
  const int ms = w >> 2;        // j-tile (0..1)
  const int ns = w & 3;         // pos-tile (0..3)
  float c1v[4];
#pragma unroll
  for (int r2 = 0; r2 < 4; ++r2) c1v[r2] = c1_g[ms*16 + lg*4 + r2];

  const f4_t fzero = {0.f, 0.f, 0.f, 0.f};
  f4_t accxa[2] = { fzero, fzero };
  float Lacc[4] = {0.f, 0.f, 0.f, 0.f};

  __syncthreads();

  for (int tile = 0; tile < 16; ++tile) {
    const float* xt = xbase + tile * (64 * 128);
#pragma unroll
    for (int i = 0; i < 4; ++i) {
      int f = tid + i*512;
      int pos = f >> 5, d0 = (f & 31) << 2;
      f4_t v = __builtin_nontemporal_load((const f4_t*)(xt + pos*128 + d0));
      bf4_t b4 = { (__bf16)v.x, (__bf16)v.y, (__bf16)v.z, (__bf16)v.w };
      *(bf4_t*)&xb[pos][d0] = b4;
    }
    __syncthreads();
    // transpose xb -> xT
#pragma unroll
    for (int s = 0; s < 2; ++s) {
      int u = tid + s*512;
      int dim = u & 127, pb = (u >> 7) << 3;
      bf8_t t8;
#pragma unroll
      for (int p = 0; p < 8; ++p) t8[p] = xb[pb + p][dim];
      *(bf8_t*)&xT[dim][pb] = t8;
    }
    // scores: ST[j=32][pos=64] = q1t(32x128) @ x^T
    f4_t sacc = fzero;
#pragma unroll
    for (int ks = 0; ks < 4; ++ks) {
      bf8_t a = *(const bf8_t*)&q1t[ms*16 + lc][ks*32 + lg*8];
      bf8_t b = *(const bf8_t*)&xb[ns*16 + lc][ks*32 + lg*8];
      sacc = MFMA16(a, b, sacc);
    }
    const int posn = ns*16 + lc;
#pragma unroll
    for (int r2 = 0; r2 < 4; ++r2) {
      float p = __expf(sacc[r2] + c1v[r2]);
      Lacc[r2] += p;
      PT[ms*16 + lg*4 + r2][posn] = (__bf16)p;
    }
    __syncthreads();
    // xa[j=32][dim=128] += P(32x64) @ x(64x128)
#pragma unroll
    for (int nt = 0; nt < 2; ++nt) {
      const int dimt = (ns << 1) + nt;
#pragma unroll
      for (int ks = 0; ks < 2; ++ks) {
        bf8_t a = *(const bf8_t*)&PT[ms*16 + lc][ks*32 + lg*8];
        bf8_t b = *(const bf8_t*)&xT[dimt*16 + lc][ks*32 + lg*8];
        accxa[nt] = MFMA16(a, b, accxa[nt]);
      }
    }
    __syncthreads();
  }

#pragma unroll
  for (int r2 = 0; r2 < 4; ++r2) {
    float v = Lacc[r2];
    v += __shfl_xor(v, 1);
    v += __shfl_xor(v, 2);
    v += __shfl_xor(v, 4);
    v += __shfl_xor(v, 8);
    if (lc == 0) atomicAdd(&lds_l[ms*16 + lg*4 + r2], v);
  }
  __syncthreads();

  float* xo = xap + (size_t)bid * 4096;
#pragma unroll
  for (int nt = 0; nt < 2; ++nt) {
    const int dim = ((ns << 1) + nt)*16 + lc;
#pragma unroll
    for (int r2 = 0; r2 < 4; ++r2) {
      int j = ms*16 + lg*4 + r2;
      xo[j*128 + dim] = accxa[nt][r2];
    }
  }
  if (tid < 32) lp[bid*32 + tid] = lds_l[tid];
}

// ---------------------------------------------------------------------------
// K1b: per-batch epilogue + stage-2 folding. One block per batch.
// Outputs kt2/vt2 as bf16.
// ---------------------------------------------------------------------------
__global__ __launch_bounds__(256) void k1b_mid(
    const float* __restrict__ xap, const float* __restrict__ lp,
    const float* __restrict__ Wv1, const float* __restrict__ bv1,
    const float* __restrict__ Wo1, const float* __restrict__ bo1,
    const float* __restrict__ Wk2, const float* __restrict__ bk2,
    const float* __restrict__ Wv2, const float* __restrict__ bv2,
    const float* __restrict__ Wq2, const float* __restrict__ bq2,
    const float* __restrict__ Wo2,
    __bf16* __restrict__ kt2, float* __restrict__ c2, __bf16* __restrict__ vt2)
{
  __shared__ float xa[32][129];
  __shared__ float invl[32];
  __shared__ float out1[8][128];
  __shared__ float rb[8][128];
  __shared__ float k2s[8][128];
  __shared__ float v2s[8][128];

  const int t = threadIdx.x, b = blockIdx.x;
  const float* p0 = xap + (size_t)(b*2) * 4096;
  const float* p1 = xap + (size_t)(b*2 + 1) * 4096;
  for (int idx = t; idx < 4096; idx += 256)
    xa[idx >> 7][idx & 127] = p0[idx] + p1[idx];
  if (t < 32) invl[t] = 1.f / (lp[b*64 + t] + lp[b*64 + 32 + t]);
  __syncthreads();

  for (int idx = t; idx < 1024; idx += 256) {
    int r = idx >> 7, hd = idx & 127, h = hd >> 5;
    int j = h*8 + r;
    float acc = 0.f;
    for (int e = 0; e < 128; ++e) acc += xa[j][e] * Wv1[e*128 + hd];
    out1[r][hd] = acc * invl[j] + bv1[hd];
  }
  __syncthreads();
  for (int idx = t; idx < 1024; idx += 256) {
    int r = idx >> 7, e2 = idx & 127;
    float acc = bo1[e2];
    for (int hd = 0; hd < 128; ++hd) acc += out1[r][hd] * Wo1[hd*128 + e2];
    rb[r][e2] = acc;
  }
  __syncthreads();
  for (int idx = t; idx < 2048; idx += 256) {
    int sel = idx >> 10;
    int r = (idx >> 7) & 7, hd = idx & 127;
    const float* W = sel ? Wv2 : Wk2;
    const float* bb = sel ? bv2 : bk2;
    float acc = bb[hd];
    for (int e = 0; e < 128; ++e) acc += rb[r][e] * W[e*128 + hd];
    float (*dst)[128] = sel ? v2s : k2s;
    dst[r][hd] = acc;
  }
  __syncthreads();
  for (int idx = t; idx < 4096; idx += 256) {
    int j = idx >> 7, e = idx & 127;
    int h = j >> 3, r = j & 7;
    float acck = 0.f, accv = 0.f;
    for (int d = 0; d < 32; ++d) {
      acck += Wq2[e*128 + h*32 + d] * k2s[r][h*32 + d];
      accv += v2s[r][h*32 + d] * Wo2[(h*32 + d)*128 + e];
    }
    kt2[(size_t)b*4096 + j*128 + e] = (__bf16)(acck * kScale);  // [j][e]
    vt2[(size_t)b*4096 + e*32 + j] = (__bf16)accv;              // [e][j]
  }
  if (t < 32) {
    int h = t >> 3, r = t & 7;
    float acc = 0.f;
    for (int d = 0; d < 32; ++d) acc += bq2[h*32 + d] * k2s[r][h*32 + d];
    c2[b*32 + t] = acc * kScale;
  }
}

// ---------------------------------------------------------------------------
// K2: stage-2 attention + residual + LayerNorm. One block = 128 positions,
// 512 threads / 8 waves; grid 4096 (16 blocks per batch).
// ---------------------------------------------------------------------------
__global__ __launch_bounds__(512) void k2_stage2(
    const float* __restrict__ Z, const __bf16* __restrict__ kt2,
    const float* __restrict__ c2g, const __bf16* __restrict__ vt2,
    const float* __restrict__ bo2, const float* __restrict__ gamma,
    const float* __restrict__ beta, float* __restrict__ out)
{
  __shared__ __bf16 xb[128][136];
  __shared__ __bf16 kt[32][136];
  __shared__ __bf16 vT[128][56];
  __shared__ __bf16 P2[128][56];

  const int tid = threadIdx.x;
  const int bid = blockIdx.x;
  const int batch = bid >> 4;
  const size_t rowbase = (size_t)bid * (128 * 128);
  const float* x = Z + rowbase;
  float* y = out + rowbase;

  // stage kt (4096 bf16): one 16B chunk per thread
  {
    int j = tid >> 4, e0 = (tid & 15) << 3;
    *(uint4*)&kt[j][e0] = *(const uint4*)(kt2 + (size_t)batch*4096 + j*128 + e0);
  }
  // stage vT (4096 bf16, [e][j] rows of 32): one 16B chunk per thread
  {
    int e = tid >> 2, j0 = (tid & 3) << 3;
    *(uint4*)&vT[e][j0] = *(const uint4*)(vt2 + (size_t)batch*4096 + e*32 + j0);
  }
  // stage x (128x128 f32 -> bf16)
  f4_t zv[8];
#pragma unroll
  for (int i = 0; i < 8; ++i) {
    int f = tid + i*512;
    int pos = f >> 5, d0 = (f & 31) << 2;
    zv[i] = __builtin_nontemporal_load((const f4_t*)(x + pos*128 + d0));
  }
#pragma unroll
  for (int i = 0; i < 8; ++i) {
    int f = tid + i*512;
    int pos = f >> 5, d0 = (f & 31) << 2;
    bf4_t b4 = { (__bf16)zv[i].x, (__bf16)zv[i].y, (__bf16)zv[i].z, (__bf16)zv[i].w };
    *(bf4_t*)&xb[pos][d0] = b4;
  }
  __syncthreads();

  const int lane = tid & 63;
  const int w = tid >> 6;    // 8 waves, pos-tile = w (16 pos each)
  const int lc = lane & 15;
  const int lg = lane >> 4;

  const f4_t fzero = {0.f, 0.f, 0.f, 0.f};

  // scores: S2[pos=128][j=32] = x @ kt^T
  f4_t sacc[2] = { fzero, fzero };
#pragma unroll
  for (int ks = 0; ks < 4; ++ks) {
    bf8_t a = *(const bf8_t*)&xb[w*16 + lc][ks*32 + lg*8];
#pragma unroll
    for (int nt = 0; nt < 2; ++nt) {
      bf8_t b = *(const bf8_t*)&kt[nt*16 + lc][ks*32 + lg*8];
      sacc[nt] = MFMA16(a, b, sacc[nt]);
    }
  }
  float c2v[2] = { c2g[batch*32 + lc], c2g[batch*32 + 16 + lc] };
  // per-head softmax over 8 routers (lanes differing in bits 0..2 of lc)
#pragma unroll
  for (int nt = 0; nt < 2; ++nt) {
#pragma unroll
    for (int r2 = 0; r2 < 4; ++r2) {
      float s = sacc[nt][r2] + c2v[nt];
      float m = s;
      m = fmaxf(m, __shfl_xor(m, 1));
      m = fmaxf(m, __shfl_xor(m, 2));
      m = fmaxf(m, __shfl_xor(m, 4));
      float p = __expf(s - m);
      float sum = p;
      sum += __shfl_xor(sum, 1);
      sum += __shfl_xor(sum, 2);
      sum += __shfl_xor(sum, 4);
      P2[w*16 + lg*4 + r2][nt*16 + lc] = (__bf16)(p / sum);
    }
  }
  __syncthreads();

  // rr[pos][dim] = P2(128x32) @ vT^T   (K=32: single MFMA per dim tile)
  bf8_t pa = *(const bf8_t*)&P2[w*16 + lc][lg*8];
  f4_t racc[8];
#pragma unroll
  for (int nt = 0; nt < 8; ++nt) {
    bf8_t b = *(const bf8_t*)&vT[nt*16 + lc][lg*8];
    racc[nt] = MFMA16(pa, b, fzero);
  }

  float bo2v[8], gv[8], bv[8];
#pragma unroll
  for (int nt = 0; nt < 8; ++nt) {
    int dd = nt*16 + lc;
    bo2v[nt] = bo2[dd]; gv[nt] = gamma[dd]; bv[nt] = beta[dd];
  }
#pragma unroll
  for (int r2 = 0; r2 < 4; ++r2) {
    int pos = w*16 + lg*4 + r2;
    float vv[8];
    float s1 = 0.f, s2 = 0.f;
#pragma unroll
    for (int nt = 0; nt < 8; ++nt) {
      float xv = (float)xb[pos][nt*16 + lc];
      float tv = racc[nt][r2] + bo2v[nt] + xv;
      vv[nt] = tv; s1 += tv; s2 += tv*tv;
    }
    s1 += __shfl_xor(s1, 1); s1 += __shfl_xor(s1, 2);
    s1 += __shfl_xor(s1, 4); s1 += __shfl_xor(s1, 8);
    s2 += __shfl_xor(s2, 1); s2 += __shfl_xor(s2, 2);
    s2 += __shfl_xor(s2, 4); s2 += __shfl_xor(s2, 8);
    float mean = s1 * (1.f/128.f);
    float var = s2 * (1.f/128.f) - mean*mean;
    float rstd = rsqrtf(var + 1e-5f);
#pragma unroll
    for (int nt = 0; nt < 8; ++nt)
      __builtin_nontemporal_store((vv[nt] - mean) * rstd * gv[nt] + bv[nt],
                                  &y[pos*128 + nt*16 + lc]);
  }
}

// ---------------------------------------------------------------------------
extern "C" void kernel_launch(void* const* d_in, const int* in_sizes, int n_in,
                              void* d_out, int out_size, void* d_ws, size_t ws_size,
                              hipStream_t stream)
{
  const float* Z     = (const float*)d_in[0];
  const float* router= (const float*)d_in[1];
  const float* Wq1   = (const float*)d_in[2];
  const float* bq1   = (const float*)d_in[3];
  const float* Wk1   = (const float*)d_in[4];
  const float* bk1   = (const float*)d_in[5];
  const float* Wv1   = (const float*)d_in[6];
  const float* bv1   = (const float*)d_in[7];
  const float* Wo1   = (const float*)d_in[8];
  const float* bo1   = (const float*)d_in[9];
  const float* Wq2   = (const float*)d_in[10];
  const float* bq2   = (const float*)d_in[11];
  const float* Wk2   = (const float*)d_in[12];
  const float* bk2   = (const float*)d_in[13];
  const float* Wv2   = (const float*)d_in[14];
  const float* bv2   = (const float*)d_in[15];
  const float* Wo2   = (const float*)d_in[16];
  const float* bo2   = (const float*)d_in[17];
  const float* gamma = (const float*)d_in[18];
  const float* beta  = (const float*)d_in[19];
  float* out = (float*)d_out;

  char* base = (char*)d_ws;
  __bf16* q1tb = (__bf16*)base;                        // 8 KB
  float*  c1   = (float*)(base + 8192);                // 128 B
  float*  c2   = (float*)(base + 8448);                // 32 KB
  float*  lp   = (float*)(base + 41216);               // 64 KB
  float*  xap  = (float*)(base + 131072);              // 8 MB
  __bf16* kt2b = (__bf16*)(base + 131072 + 8388608);   // 2 MB
  __bf16* vt2b = (__bf16*)(base + 131072 + 8388608 + 2097152); // 2 MB
  (void)in_sizes; (void)n_in; (void)out_size; (void)ws_size;

  k0_fold<<<dim3(1), dim3(256), 0, stream>>>(router, Wq1, bq1, Wk1, bk1, q1tb, c1);
  k1_stage1<<<dim3(512), dim3(512), 0, stream>>>(Z, q1tb, c1, xap, lp);
  k1b_mid<<<dim3(256), dim3(256), 0, stream>>>(xap, lp, Wv1, bv1, Wo1, bo1,
                                               Wk2, bk2, Wv2, bv2, Wq2, bq2, Wo2,
                                               kt2b, c2, vt2b);
  k2_stage2<<<dim3(4096), dim3(512), 0, stream>>>(Z, kt2b, c2, vt2b, bo2, gamma, beta, out);
}